// Round 9
// baseline (2501.078 us; speedup 1.0000x reference)
//
#include <hip/hip_runtime.h>
#include <hip/hip_bf16.h>
#include <math.h>

#define VOCABSZ 30000
#define EMB 300
#define HDIM 512
#define HH 256
#define G4 1024      // 4*HH
#define BB 128
#define LL 128
#define NN 16384     // BB*LL
#define SS 10
#define NLAYERS 7

typedef _Float16 f16;
typedef _Float16 half8 __attribute__((ext_vector_type(8)));
typedef float floatx4 __attribute__((ext_vector_type(4)));

// ---- workspace float-index offsets (fp32 region) ----
#define OFF_XPF    0ll            // 16384x1024 f32 (64 MB)
#define OFF_XPB    16777216ll     // 16384x1024 f32 (64 MB)
#define WSB_WHH16  134217728ll    // byte offset: 2 x 262144 f16 = 1 MB
#define OFF_BSUM_F 34078720ll     // 1024 f32
#define OFF_BSUM_B 34079744ll
#define OFF_LENF   34080768ll     // 16384 f32
#define OFF_LENB   34097152ll     // ends at float 34113536 = byte 136454144
// ---- byte offsets for f16 region ----
#define WSB_MEAN     0ll                  // 16384x512 f16 (overlays dead xp)
#define WSB_H0       33554432ll           // 4 bufs x (NN+1)x512 f16
#define HBUF_HALVES  8389120ll            // (NN+1)*512
#define HBUF_BYTES   16778240ll
#define WSB_WF16     136454144ll          // 14 x 512x1024 f16 weights
#define WF16_PER_DIR 3670016ll            // 7*512*1024 halves
// total ws requirement: 151,134,208 bytes

// ---- d_out offsets (floats) ----
#define HID_OFF 0ll
#define GE_OFF  16777216ll
#define OV_OFF  16908288ll

__device__ __forceinline__ float sigf(float x) { return 1.0f / (1.0f + expf(-x)); }

// ---------------------------------------------------------------------------
// K0: Whh -> f16 (natural [j][k] layout, stride 256), bias sums.
// ---------------------------------------------------------------------------
__global__ __launch_bounds__(256) void k_prep(const float* __restrict__ Whh_f,
                                              const float* __restrict__ Whh_b,
                                              const float* __restrict__ bih_f,
                                              const float* __restrict__ bhh_f,
                                              const float* __restrict__ bih_b,
                                              const float* __restrict__ bhh_b,
                                              float* __restrict__ ws,
                                              f16* __restrict__ whh16) {
    long i = (long)blockIdx.x * 256 + threadIdx.x;
    if (i < 262144) {
        whh16[i] = (f16)Whh_f[i];
    } else if (i < 524288) {
        whh16[i] = (f16)Whh_b[i - 262144];
    } else if (i < 525312) {
        int j = (int)(i - 524288);
        ws[OFF_BSUM_F + j] = bih_f[j] + bhh_f[j];
    } else if (i < 526336) {
        int j = (int)(i - 525312);
        ws[OFF_BSUM_B + j] = bih_b[j] + bhh_b[j];
    }
}

// ---------------------------------------------------------------------------
// K0b: convert fw_W / bw_W (fp32) -> f16. 3584 blocks per dir.
// ---------------------------------------------------------------------------
__global__ __launch_bounds__(256) void k_wconv(const float* __restrict__ fw_W,
                                               const float* __restrict__ bw_W,
                                               f16* __restrict__ dst) {
    const int b = blockIdx.x;
    const int dir = (b >= 3584);
    const float* __restrict__ src = dir ? bw_W : fw_W;
    f16* __restrict__ d = dst + (dir ? WF16_PER_DIR : 0);
    long e = (long)(dir ? b - 3584 : b) * 1024 + (long)threadIdx.x * 4;
    float4 v = *(const float4*)(src + e);
    f16 o[4] = {(f16)v.x, (f16)v.y, (f16)v.z, (f16)v.w};
    *(float2*)(d + e) = *(float2*)o;
}

// ---------------------------------------------------------------------------
// K1: xp = emb @ Wih^T + (bih+bhh)  (fp32; bias INCLUDED here)
// ---------------------------------------------------------------------------
__global__ __launch_bounds__(256) void k_xp(const int* __restrict__ feat,
                                            const float* __restrict__ W_emb,
                                            const float* __restrict__ Wih_f,
                                            const float* __restrict__ Wih_b,
                                            float* __restrict__ ws) {
    const int m0 = blockIdx.x * 64;
    const int j0 = blockIdx.y * 64;            // 0..2047
    __shared__ float As[20][64];
    __shared__ float Bs[20][64];
    __shared__ int toks[64];
    const int tid = threadIdx.x;
    const int tx = tid & 15, ty = tid >> 4;
    if (tid < 64) toks[tid] = feat[m0 + tid];

    const int isF = (j0 < G4);
    const float* __restrict__ Wsrc = isF ? Wih_f : Wih_b;
    const int jb = isF ? j0 : j0 - G4;

    float acc[4][4] = {};
    for (int k0 = 0; k0 < 300; k0 += 20) {
        __syncthreads();
        for (int e = tid; e < 1280; e += 256) {
            int m = e / 20, k = e % 20;
            As[k][m] = W_emb[(long)toks[m] * EMB + k0 + k];
        }
        for (int e = tid; e < 1280; e += 256) {
            int j = e / 20, k = e % 20;
            Bs[k][j] = Wsrc[(long)(jb + j) * EMB + k0 + k];
        }
        __syncthreads();
#pragma unroll
        for (int k = 0; k < 20; ++k) {
            float a[4], b[4];
            *(float4*)a = *(const float4*)&As[k][ty * 4];
            *(float4*)b = *(const float4*)&Bs[k][tx * 4];
#pragma unroll
            for (int ii = 0; ii < 4; ++ii)
#pragma unroll
                for (int jj = 0; jj < 4; ++jj) acc[ii][jj] += a[ii] * b[jj];
        }
    }
    float* __restrict__ xp = ws + (isF ? OFF_XPF : OFF_XPB);
    const float* __restrict__ bs = ws + (isF ? OFF_BSUM_F : OFF_BSUM_B);
    float bv[4];
    *(float4*)bv = *(const float4*)&bs[jb + tx * 4];
#pragma unroll
    for (int ii = 0; ii < 4; ++ii) {
        long m = m0 + ty * 4 + ii;
        float4 o;
        o.x = acc[ii][0] + bv[0]; o.y = acc[ii][1] + bv[1];
        o.z = acc[ii][2] + bv[2]; o.w = acc[ii][3] + bv[3];
        *(float4*)&xp[m * G4 + jb + tx * 4] = o;
    }
}

// ---------------------------------------------------------------------------
// K2: BiLSTM scan via f16 MFMA, pipelined.
// 16 blocks = 2 dirs x 8 groups of 16 batches, 512 threads (8 waves).
// Per step: GEMM M=16 x N=1024 x K=256. t in {0,1} LDS-resident; t in {2..7}
// streamed via a 3-slot 2-deep register ring. Ping-pong hbuf -> 1 barrier.
// Next-step sB(kk=0,1) + xp loads issued before the h-update (latency soak).
// ---------------------------------------------------------------------------
__global__ __launch_bounds__(512, 2) void k_lstm(const float* __restrict__ ws_ro,
                                                 const f16* __restrict__ whh16,
                                                 float* __restrict__ out) {
    const int dir = blockIdx.x >> 3;
    const int grp = blockIdx.x & 7;
    const int bid0 = grp * 16;
    const int tid = threadIdx.x;
    const int wv = tid >> 6, lane = tid & 63;
    const int n = lane & 15, kg = lane >> 4;

    __shared__ __align__(16) f16 ldsB[128 * 512];   // 128 KB: t=0,1 frag-major
    __shared__ __align__(16) f16 hbuf[2][8 * 512];  // 16 KB ping-pong A-frags

    const f16* __restrict__ whh = whh16 + (long)dir * 262144;
    const float* __restrict__ xp = ws_ro + (dir ? OFF_XPB : OFF_XPF);
    float* __restrict__ ov = out + OV_OFF;

    // per-thread base pointers for streamed tiles t=2..7
    const f16* wbase[6];
#pragma unroll
    for (int t = 2; t < 8; ++t)
        wbase[t - 2] = whh + (long)(16 * wv + 128 * t + n) * 256 + kg * 8;

    // stage resident B frags (t=0,1): wave wv stages fids [wv*16, wv*16+16)
#pragma unroll
    for (int i = 0; i < 16; ++i) {
        const int fid = wv * 16 + i;
        const int t = fid >> 6, w = (fid >> 3) & 7, kk = fid & 7;
        const int j = 16 * w + 128 * t + n;
        *(half8*)&ldsB[fid * 512 + lane * 8] =
            *(const half8*)(whh + (long)j * 256 + kk * 32 + kg * 8);
    }
    { half8 z = {}; *(half8*)&hbuf[0][tid * 8] = z; }

    float cst[8] = {};
    float xpv[8][4], xpn[8][4];
    half8 sB[3][6];

    {   // preloads for ts = 0
        const int t0s = dir ? 127 : 0;
#pragma unroll
        for (int t = 0; t < 6; ++t) sB[0][t] = *(const half8*)(wbase[t]);
#pragma unroll
        for (int t = 0; t < 6; ++t) sB[1][t] = *(const half8*)(wbase[t] + 32);
#pragma unroll
        for (int t = 0; t < 8; ++t)
#pragma unroll
            for (int r = 0; r < 4; ++r)
                xpv[t][r] = xp[((long)(bid0 + kg * 4 + r) * 128 + t0s) * 1024
                               + 16 * wv + 128 * t + n];
    }
    int p = 0;
    __syncthreads();

    for (int ts = 0; ts < 128; ++ts) {
        const int tstep = dir ? (127 - ts) : ts;
        floatx4 acc[8] = {};
#pragma unroll
        for (int kk = 0; kk < 8; ++kk) {
            const int cur = kk % 3;
            if (kk < 6) {
                const int nslot = (kk + 2) % 3;
#pragma unroll
                for (int t = 0; t < 6; ++t)
                    sB[nslot][t] = *(const half8*)(wbase[t] + (kk + 2) * 32);
            }
            half8 a  = *(const half8*)&hbuf[p][kk * 512 + lane * 8];
            half8 b0 = *(const half8*)&ldsB[(((0 << 6) | (wv << 3) | kk)) * 512 + lane * 8];
            half8 b1 = *(const half8*)&ldsB[(((1 << 6) | (wv << 3) | kk)) * 512 + lane * 8];
            acc[0] = __builtin_amdgcn_mfma_f32_16x16x32_f16(a, b0, acc[0], 0, 0, 0);
            acc[1] = __builtin_amdgcn_mfma_f32_16x16x32_f16(a, b1, acc[1], 0, 0, 0);
#pragma unroll
            for (int t = 2; t < 8; ++t)
                acc[t] = __builtin_amdgcn_mfma_f32_16x16x32_f16(a, sB[cur][t - 2], acc[t], 0, 0, 0);
        }

        // issue next-step loads: sB(kk=0,1) FIRST, then xp (vmcnt FIFO: waits
        // on these land only next step, after the h-update has soaked latency)
        if (ts < 127) {
            const int tnx = dir ? (127 - (ts + 1)) : (ts + 1);
#pragma unroll
            for (int t = 0; t < 6; ++t) sB[0][t] = *(const half8*)(wbase[t]);
#pragma unroll
            for (int t = 0; t < 6; ++t) sB[1][t] = *(const half8*)(wbase[t] + 32);
#pragma unroll
            for (int t = 0; t < 8; ++t)
#pragma unroll
                for (int r = 0; r < 4; ++r)
                    xpn[t][r] = xp[((long)(bid0 + kg * 4 + r) * 128 + tnx) * 1024
                                   + 16 * wv + 128 * t + n];
        }

        // h / c update (all 4 gates of unit u live in this lane)
#pragma unroll
        for (int t0 = 0; t0 < 2; ++t0) {
            const int u = 128 * t0 + 16 * wv + n;
            const int kkw = u >> 5;
            const int lgrp = 16 * ((u >> 3) & 3);
            const int e = u & 7;
#pragma unroll
            for (int r = 0; r < 4; ++r) {
                float gi = acc[t0][r]     + xpv[t0][r];
                float gf = acc[t0 + 2][r] + xpv[t0 + 2][r];
                float gg = acc[t0 + 4][r] + xpv[t0 + 4][r];
                float go = acc[t0 + 6][r] + xpv[t0 + 6][r];
                float c = cst[t0 * 4 + r];
                c = sigf(gf) * c + sigf(gi) * tanhf(gg);
                cst[t0 * 4 + r] = c;
                float h = sigf(go) * tanhf(c);
                hbuf[p ^ 1][kkw * 512 + (kg * 4 + r + lgrp) * 8 + e] = (f16)h;
                ov[((long)(bid0 + kg * 4 + r) * 128 + tstep) * 512 + dir * 256 + u] = h;
            }
        }
        __syncthreads();
#pragma unroll
        for (int t = 0; t < 8; ++t)
#pragma unroll
            for (int r = 0; r < 4; ++r) xpv[t][r] = xpn[t][r];
        p ^= 1;
    }
}

// ---------------------------------------------------------------------------
// K3: fw_hidden = bw_hidden = f16(node_repres[nodes]); zero row NN of all
// four hidden buffers (runs AFTER lstm, so the xp-overlay is safe).
// ---------------------------------------------------------------------------
__global__ __launch_bounds__(256) void k_init(const int* __restrict__ nodes,
                                              const float* __restrict__ padding,
                                              const float* __restrict__ out_ro,
                                              f16* __restrict__ h0) {
    long i = (long)blockIdx.x * 256 + threadIdx.x;
    if (i >= (long)NN * 64 + 256) return;
    if (i >= (long)NN * 64) {
        int e = (int)(i - (long)NN * 64);      // 0..255
        int buf = e >> 6, c = (e & 63) * 8;
        half8 z = {};
        *(half8*)(h0 + (long)buf * HBUF_HALVES + (long)NN * HDIM + c) = z;
        return;
    }
    int ni = (int)(i >> 6), c = (int)(i & 63) * 8;
    int r = nodes[ni];
    const float* src = (r < NN) ? (out_ro + OV_OFF + (long)r * HDIM + c)
                                : (padding + c);
    float4 v0 = *(const float4*)src;
    float4 v1 = *(const float4*)(src + 4);
    half8 h;
    h[0] = (f16)v0.x; h[1] = (f16)v0.y; h[2] = (f16)v0.z; h[3] = (f16)v0.w;
    h[4] = (f16)v1.x; h[5] = (f16)v1.y; h[6] = (f16)v1.z; h[7] = (f16)v1.w;
    *(half8*)(h0 + (long)ni * HDIM + c) = h;                      // fw buf 0
    *(half8*)(h0 + 2 * HBUF_HALVES + (long)ni * HDIM + c) = h;    // bw buf 0
}

// ---------------------------------------------------------------------------
// K4a: neighbor mean (+ len at layer 0). One wave per node, 4 nodes/block.
// ---------------------------------------------------------------------------
__global__ __launch_bounds__(256) void k_mean(const int* __restrict__ adj,
                                              const int* __restrict__ nodes,
                                              const f16* __restrict__ src,
                                              const float* __restrict__ ov,
                                              const float* __restrict__ padding,
                                              f16* __restrict__ mean,
                                              float* __restrict__ len,
                                              int layer0) {
    const int w = threadIdx.x >> 6;
    const int lane = threadIdx.x & 63;
    const int i = blockIdx.x * 4 + w;
    const int p0 = lane * 8;
    const int node = nodes[i];
    float acc[8] = {};
    float cnt = 0.0f;
    for (int s = 0; s < SS; ++s) {
        const int r = adj[(long)node * SS + s];
        if (layer0) {
            const float* row = (r < NN) ? (ov + (long)r * HDIM) : padding;
            float4 v0 = *(const float4*)(row + p0);
            float4 v1 = *(const float4*)(row + p0 + 4);
            acc[0] += v0.x; acc[1] += v0.y; acc[2] += v0.z; acc[3] += v0.w;
            acc[4] += v1.x; acc[5] += v1.y; acc[6] += v1.z; acc[7] += v1.w;
            float rs = fmaxf(v0.x, 0.f) + fmaxf(v0.y, 0.f) + fmaxf(v0.z, 0.f) + fmaxf(v0.w, 0.f)
                     + fmaxf(v1.x, 0.f) + fmaxf(v1.y, 0.f) + fmaxf(v1.z, 0.f) + fmaxf(v1.w, 0.f);
#pragma unroll
            for (int off = 32; off; off >>= 1) rs += __shfl_xor(rs, off);
            cnt += (rs > 0.0f) ? 1.0f : 0.0f;
        } else {
            half8 v = *(const half8*)(src + (long)r * HDIM + p0);
#pragma unroll
            for (int j = 0; j < 8; ++j) acc[j] += (float)v[j];
        }
    }
    float ln;
    if (layer0) {
        if (lane == 0) len[i] = cnt;
        ln = cnt;
    } else {
        ln = len[i];
    }
    half8 o;
#pragma unroll
    for (int j = 0; j < 8; ++j) o[j] = (f16)(acc[j] / ln);
    *(half8*)(mean + (long)i * HDIM + p0) = o;
}

// ---------------------------------------------------------------------------
// K4b: out = relu(concat[self, mean] @ W^T + b) via f16 MFMA.
// M=16384, N=512, K=1024. Tile BM=128 x BN=128, BK=64. 4 waves (2x2),
// each wave owns a 64x64 sub-tile (16 MFMAs per 32-K slice).
// LDS rows padded to 72 halves (144 B: aligned b128, 2-way banks = free).
// ---------------------------------------------------------------------------
__global__ __launch_bounds__(256) void k_sage(const f16* __restrict__ selfH,
                                              const f16* __restrict__ meanH,
                                              const f16* __restrict__ WH,
                                              const float* __restrict__ bl,
                                              f16* __restrict__ outH) {
    const int m0 = blockIdx.x * 128;
    const int q0 = blockIdx.y * 128;
    __shared__ __align__(16) f16 At[128 * 72];
    __shared__ __align__(16) f16 Bt[128 * 72];
    const int tid = threadIdx.x;
    const int wid = tid >> 6;
    const int lane = tid & 63;
    const int wr = wid >> 1, wc = wid & 1;
    const int ln15 = lane & 15, hi = lane >> 4;
    // staging: thread loads 32 halves of A and 32 of B (128 rows x 64 cols each)
    const int ar = tid >> 1, acS = (tid & 1) * 32;

    floatx4 acc[4][4] = {};
    float4 av0, av1, av2, av3, bv0, bv1, bv2, bv3;

    // preload k0 = 0 (k<512 -> selfH)
    {
        const f16* as = selfH + ((long)(m0 + ar) << 9) + acS;
        av0 = *(const float4*)(const void*)as;
        av1 = *(const float4*)(const void*)(as + 8);
        av2 = *(const float4*)(const void*)(as + 16);
        av3 = *(const float4*)(const void*)(as + 24);
        const f16* bs = WH + ((long)(q0 + ar) << 10) + acS;
        bv0 = *(const float4*)(const void*)bs;
        bv1 = *(const float4*)(const void*)(bs + 8);
        bv2 = *(const float4*)(const void*)(bs + 16);
        bv3 = *(const float4*)(const void*)(bs + 24);
    }

    for (int k0 = 0; k0 < 1024; k0 += 64) {
        __syncthreads();
        *(float4*)(void*)&At[ar * 72 + acS]      = av0;
        *(float4*)(void*)&At[ar * 72 + acS + 8]  = av1;
        *(float4*)(void*)&At[ar * 72 + acS + 16] = av2;
        *(float4*)(void*)&At[ar * 72 + acS + 24] = av3;
        *(float4*)(void*)&Bt[ar * 72 + acS]      = bv0;
        *(float4*)(void*)&Bt[ar * 72 + acS + 8]  = bv1;
        *(float4*)(void*)&Bt[ar * 72 + acS + 16] = bv2;
        *(float4*)(void*)&Bt[ar * 72 + acS + 24] = bv3;
        __syncthreads();

        if (k0 + 64 < 1024) {
            const int kn = k0 + 64;
            const f16* as = (kn < 512)
                ? selfH + ((long)(m0 + ar) << 9) + kn + acS
                : meanH + ((long)(m0 + ar) << 9) + (kn - 512) + acS;
            av0 = *(const float4*)(const void*)as;
            av1 = *(const float4*)(const void*)(as + 8);
            av2 = *(const float4*)(const void*)(as + 16);
            av3 = *(const float4*)(const void*)(as + 24);
            const f16* bs = WH + ((long)(q0 + ar) << 10) + kn + acS;
            bv0 = *(const float4*)(const void*)bs;
            bv1 = *(const float4*)(const void*)(bs + 8);
            bv2 = *(const float4*)(const void*)(bs + 16);
            bv3 = *(const float4*)(const void*)(bs + 24);
        }

#pragma unroll
        for (int ks = 0; ks < 2; ++ks) {
            half8 a[4], b[4];
#pragma unroll
            for (int mi = 0; mi < 4; ++mi)
                a[mi] = *(const half8*)(const void*)&At[(wr * 64 + mi * 16 + ln15) * 72 + ks * 32 + hi * 8];
#pragma unroll
            for (int ni = 0; ni < 4; ++ni)
                b[ni] = *(const half8*)(const void*)&Bt[(wc * 64 + ni * 16 + ln15) * 72 + ks * 32 + hi * 8];
#pragma unroll
            for (int mi = 0; mi < 4; ++mi)
#pragma unroll
                for (int ni = 0; ni < 4; ++ni)
                    acc[mi][ni] = __builtin_amdgcn_mfma_f32_16x16x32_f16(a[mi], b[ni], acc[mi][ni], 0, 0, 0);
        }
    }

    // epilogue: bias + relu, write f16
#pragma unroll
    for (int ni = 0; ni < 4; ++ni) {
        const int gc = q0 + wc * 64 + ni * 16 + ln15;
        const float bv = bl[gc];
#pragma unroll
        for (int mi = 0; mi < 4; ++mi) {
            const int gr = m0 + wr * 64 + mi * 16 + hi * 4;
#pragma unroll
            for (int r = 0; r < 4; ++r) {
                float v = acc[mi][ni][r] + bv;
                v = fmaxf(v, 0.0f);
                outH[(long)(gr + r) * HDIM + gc] = (f16)v;
            }
        }
    }
}

// ---------------------------------------------------------------------------
// K5: hidden = concat[fw, bw] (B,L,1024) fp32; graph_embedding = max over L.
// ---------------------------------------------------------------------------
__global__ __launch_bounds__(256) void k_final(const f16* __restrict__ fwF,
                                               const f16* __restrict__ bwF,
                                               float* __restrict__ out) {
    const int b = blockIdx.x >> 2;
    const int j = (blockIdx.x & 3) * 256 + threadIdx.x;   // 0..1023
    const f16* __restrict__ src = (j < HDIM) ? fwF : bwF;
    const int jj = (j < HDIM) ? j : j - HDIM;
    float mx = -INFINITY;
    float* __restrict__ hid = out + HID_OFF;
#pragma unroll 4
    for (int l = 0; l < LL; ++l) {
        float v = (float)src[(long)(b * LL + l) * HDIM + jj];
        hid[(long)b * LL * 1024 + (long)l * 1024 + j] = v;
        mx = fmaxf(mx, v);
    }
    out[GE_OFF + (long)b * 1024 + j] = mx;
}

// ---------------------------------------------------------------------------
extern "C" void kernel_launch(void* const* d_in, const int* in_sizes, int n_in,
                              void* d_out, int out_size, void* d_ws, size_t ws_size,
                              hipStream_t stream) {
    const int*   feature_info = (const int*)d_in[0];
    const int*   batch_nodes  = (const int*)d_in[1];
    const int*   fw_adj       = (const int*)d_in[2];
    const int*   bw_adj       = (const int*)d_in[3];
    const float* W_emb        = (const float*)d_in[4];
    const float* Wih_f        = (const float*)d_in[5];
    const float* Whh_f        = (const float*)d_in[6];
    const float* bih_f        = (const float*)d_in[7];
    const float* bhh_f        = (const float*)d_in[8];
    const float* Wih_b        = (const float*)d_in[9];
    const float* Whh_b        = (const float*)d_in[10];
    const float* bih_b        = (const float*)d_in[11];
    const float* bhh_b        = (const float*)d_in[12];
    const float* padding      = (const float*)d_in[13];
    const float* fw_W         = (const float*)d_in[14];
    const float* fw_bias      = (const float*)d_in[15];
    const float* bw_W         = (const float*)d_in[16];
    const float* bw_bias      = (const float*)d_in[17];
    float* out = (float*)d_out;
    float* ws  = (float*)d_ws;
    char*  wsb = (char*)d_ws;

    f16* h0    = (f16*)(wsb + WSB_H0);
    f16* wf16  = (f16*)(wsb + WSB_WF16);
    f16* meanH = (f16*)(wsb + WSB_MEAN);
    f16* whh16 = (f16*)(wsb + WSB_WHH16);
    f16* fwH[2] = { h0,                    h0 + HBUF_HALVES };
    f16* bwH[2] = { h0 + 2 * HBUF_HALVES,  h0 + 3 * HBUF_HALVES };

    k_prep<<<2056, 256, 0, stream>>>(Whh_f, Whh_b, bih_f, bhh_f, bih_b, bhh_b, ws, whh16);
    k_wconv<<<7168, 256, 0, stream>>>(fw_W, bw_W, wf16);
    k_xp<<<dim3(256, 32), 256, 0, stream>>>(feature_info, W_emb, Wih_f, Wih_b, ws);
    k_lstm<<<16, 512, 0, stream>>>(ws, whh16, out);
    k_init<<<4097, 256, 0, stream>>>(batch_nodes, padding, out, h0);

    int fc = 0, bc = 0;
    for (int l = 0; l < NLAYERS; ++l) {
        k_mean<<<4096, 256, 0, stream>>>(fw_adj, batch_nodes, fwH[fc], out + OV_OFF,
                                         padding, meanH, ws + OFF_LENF, l == 0);
        k_sage<<<dim3(128, 4), 256, 0, stream>>>(fwH[fc], meanH,
                                                 wf16 + (long)l * HDIM * G4,
                                                 fw_bias + (long)l * HDIM, fwH[fc ^ 1]);
        fc ^= 1;
        k_mean<<<4096, 256, 0, stream>>>(bw_adj, batch_nodes, bwH[bc], out + OV_OFF,
                                         padding, meanH, ws + OFF_LENB, l == 0);
        k_sage<<<dim3(128, 4), 256, 0, stream>>>(bwH[bc], meanH,
                                                 wf16 + WF16_PER_DIR + (long)l * HDIM * G4,
                                                 bw_bias + (long)l * HDIM, bwH[bc ^ 1]);
        bc ^= 1;
    }
    k_final<<<512, 256, 0, stream>>>(fwH[fc], bwH[bc], out);
}

// Round 10
// 1867.608 us; speedup vs baseline: 1.3392x; 1.3392x over previous
//
#include <hip/hip_runtime.h>
#include <hip/hip_bf16.h>
#include <math.h>

#define VOCABSZ 30000
#define EMB 300
#define HDIM 512
#define HH 256
#define G4 1024      // 4*HH
#define BB 128
#define LL 128
#define NN 16384     // BB*LL
#define SS 10
#define NLAYERS 7

typedef _Float16 f16;
typedef _Float16 half8 __attribute__((ext_vector_type(8)));
typedef float floatx4 __attribute__((ext_vector_type(4)));

// ---- workspace float-index offsets (fp32 region) ----
#define OFF_XPF    0ll            // 16384x1024 f32 (64 MB)
#define OFF_XPB    16777216ll     // 16384x1024 f32 (64 MB)
#define WSB_WHH16  134217728ll    // byte offset: 2 x 262144 f16 = 1 MB
#define OFF_BSUM_F 34078720ll     // 1024 f32
#define OFF_BSUM_B 34079744ll
#define OFF_LENF   34080768ll     // 16384 f32
#define OFF_LENB   34097152ll     // ends at float 34113536 = byte 136454144
// ---- byte offsets for f16 region ----
#define WSB_MEAN     0ll                  // 16384x512 f16 (overlays dead xp)
#define WSB_H0       33554432ll           // 4 bufs x (NN+1)x512 f16
#define HBUF_HALVES  8389120ll            // (NN+1)*512
#define HBUF_BYTES   16778240ll
#define WSB_WF16     136454144ll          // 14 x 512x1024 f16 weights
#define WF16_PER_DIR 3670016ll            // 7*512*1024 halves
// total ws requirement: 151,134,208 bytes

// ---- d_out offsets (floats) ----
#define HID_OFF 0ll
#define GE_OFF  16777216ll
#define OV_OFF  16908288ll

__device__ __forceinline__ float sigf(float x) { return 1.0f / (1.0f + expf(-x)); }

// ---------------------------------------------------------------------------
// K0: Whh -> f16 (natural [j][k] layout, stride 256), bias sums.
// ---------------------------------------------------------------------------
__global__ __launch_bounds__(256) void k_prep(const float* __restrict__ Whh_f,
                                              const float* __restrict__ Whh_b,
                                              const float* __restrict__ bih_f,
                                              const float* __restrict__ bhh_f,
                                              const float* __restrict__ bih_b,
                                              const float* __restrict__ bhh_b,
                                              float* __restrict__ ws,
                                              f16* __restrict__ whh16) {
    long i = (long)blockIdx.x * 256 + threadIdx.x;
    if (i < 262144) {
        whh16[i] = (f16)Whh_f[i];
    } else if (i < 524288) {
        whh16[i] = (f16)Whh_b[i - 262144];
    } else if (i < 525312) {
        int j = (int)(i - 524288);
        ws[OFF_BSUM_F + j] = bih_f[j] + bhh_f[j];
    } else if (i < 526336) {
        int j = (int)(i - 525312);
        ws[OFF_BSUM_B + j] = bih_b[j] + bhh_b[j];
    }
}

// ---------------------------------------------------------------------------
// K0b: convert fw_W / bw_W (fp32) -> f16. 3584 blocks per dir.
// ---------------------------------------------------------------------------
__global__ __launch_bounds__(256) void k_wconv(const float* __restrict__ fw_W,
                                               const float* __restrict__ bw_W,
                                               f16* __restrict__ dst) {
    const int b = blockIdx.x;
    const int dir = (b >= 3584);
    const float* __restrict__ src = dir ? bw_W : fw_W;
    f16* __restrict__ d = dst + (dir ? WF16_PER_DIR : 0);
    long e = (long)(dir ? b - 3584 : b) * 1024 + (long)threadIdx.x * 4;
    float4 v = *(const float4*)(src + e);
    f16 o[4] = {(f16)v.x, (f16)v.y, (f16)v.z, (f16)v.w};
    *(float2*)(d + e) = *(float2*)o;
}

// ---------------------------------------------------------------------------
// K1: xp = emb @ Wih^T + (bih+bhh)  (fp32; bias INCLUDED here)
// ---------------------------------------------------------------------------
__global__ __launch_bounds__(256) void k_xp(const int* __restrict__ feat,
                                            const float* __restrict__ W_emb,
                                            const float* __restrict__ Wih_f,
                                            const float* __restrict__ Wih_b,
                                            float* __restrict__ ws) {
    const int m0 = blockIdx.x * 64;
    const int j0 = blockIdx.y * 64;            // 0..2047
    __shared__ float As[20][64];
    __shared__ float Bs[20][64];
    __shared__ int toks[64];
    const int tid = threadIdx.x;
    const int tx = tid & 15, ty = tid >> 4;
    if (tid < 64) toks[tid] = feat[m0 + tid];

    const int isF = (j0 < G4);
    const float* __restrict__ Wsrc = isF ? Wih_f : Wih_b;
    const int jb = isF ? j0 : j0 - G4;

    float acc[4][4] = {};
    for (int k0 = 0; k0 < 300; k0 += 20) {
        __syncthreads();
        for (int e = tid; e < 1280; e += 256) {
            int m = e / 20, k = e % 20;
            As[k][m] = W_emb[(long)toks[m] * EMB + k0 + k];
        }
        for (int e = tid; e < 1280; e += 256) {
            int j = e / 20, k = e % 20;
            Bs[k][j] = Wsrc[(long)(jb + j) * EMB + k0 + k];
        }
        __syncthreads();
#pragma unroll
        for (int k = 0; k < 20; ++k) {
            float a[4], b[4];
            *(float4*)a = *(const float4*)&As[k][ty * 4];
            *(float4*)b = *(const float4*)&Bs[k][tx * 4];
#pragma unroll
            for (int ii = 0; ii < 4; ++ii)
#pragma unroll
                for (int jj = 0; jj < 4; ++jj) acc[ii][jj] += a[ii] * b[jj];
        }
    }
    float* __restrict__ xp = ws + (isF ? OFF_XPF : OFF_XPB);
    const float* __restrict__ bs = ws + (isF ? OFF_BSUM_F : OFF_BSUM_B);
    float bv[4];
    *(float4*)bv = *(const float4*)&bs[jb + tx * 4];
#pragma unroll
    for (int ii = 0; ii < 4; ++ii) {
        long m = m0 + ty * 4 + ii;
        float4 o;
        o.x = acc[ii][0] + bv[0]; o.y = acc[ii][1] + bv[1];
        o.z = acc[ii][2] + bv[2]; o.w = acc[ii][3] + bv[3];
        *(float4*)&xp[m * G4 + jb + tx * 4] = o;
    }
}

// ---------------------------------------------------------------------------
// K2: BiLSTM scan via f16 MFMA, 128 blocks = 2 dirs x 64 groups of 2 batches.
// 512 threads (8 waves). Per step: GEMM M=16(2 valid) x N=1024 x K=256.
// Whh: t=0,1 LDS-resident (128 KB); t=2..5 REGISTER-resident (128 VGPR/lane);
// t=6,7 streamed from L2 (128 KB/step, 1-deep prefetch). Ping-pong hbuf,
// 1 barrier/step. All 4 gates of a unit land in one lane (in-reg c/h update).
// 8x more CUs than the 16-block version -> 8x the memory-level parallelism.
// ---------------------------------------------------------------------------
__global__ __launch_bounds__(512, 2) void k_lstm(const float* __restrict__ ws_ro,
                                                 const f16* __restrict__ whh16,
                                                 float* __restrict__ out) {
    const int dir = blockIdx.x >> 6;
    const int grp = blockIdx.x & 63;
    const int bid0 = grp * 2;
    const int tid = threadIdx.x;
    const int wv = tid >> 6, lane = tid & 63;
    const int n = lane & 15, kg = lane >> 4;

    __shared__ __align__(16) f16 ldsB[128 * 512];   // 128 KB: t=0,1 frag-major
    __shared__ __align__(16) f16 hbuf[2][8 * 512];  // 16 KB ping-pong A-frags

    const f16* __restrict__ whh = whh16 + (long)dir * 262144;
    const float* __restrict__ xp = ws_ro + (dir ? OFF_XPB : OFF_XPF);
    float* __restrict__ ov = out + OV_OFF;

    // register-resident Whh tiles t=2..5 (each wave holds only its 16 rows)
    half8 wreg[4][8];
#pragma unroll
    for (int t = 2; t < 6; ++t)
#pragma unroll
        for (int kk = 0; kk < 8; ++kk)
            wreg[t - 2][kk] = *(const half8*)(whh + (long)(16 * wv + 128 * t + n) * 256
                                              + kk * 32 + kg * 8);
    // stream bases for t=6,7
    const f16* __restrict__ wbase6 = whh + (long)(16 * wv + 128 * 6 + n) * 256 + kg * 8;
    const f16* __restrict__ wbase7 = whh + (long)(16 * wv + 128 * 7 + n) * 256 + kg * 8;

    // stage LDS-resident t=0,1: wave wv stages fids [wv*16, wv*16+16)
#pragma unroll
    for (int i = 0; i < 16; ++i) {
        const int fid = wv * 16 + i;
        const int t = fid >> 6, w = (fid >> 3) & 7, kk = fid & 7;
        const int j = 16 * w + 128 * t + n;
        *(half8*)&ldsB[fid * 512 + lane * 8] =
            *(const half8*)(whh + (long)j * 256 + kk * 32 + kg * 8);
    }
    {   // zero BOTH hbuf buffers: rows m>=2 must stay 0 forever
        half8 z = {};
        *(half8*)&hbuf[0][tid * 8] = z;
        *(half8*)&hbuf[1][tid * 8] = z;
    }
    float cst[4] = {};
    int p = 0;
    __syncthreads();

    for (int ts = 0; ts < 128; ++ts) {
        const int tstep = dir ? (127 - ts) : ts;

        // current-step xp (valid rows only) — hidden under the MFMA loop
        float xpv[8][2];
        if (kg == 0) {
#pragma unroll
            for (int t = 0; t < 8; ++t)
#pragma unroll
                for (int r = 0; r < 2; ++r)
                    xpv[t][r] = xp[((long)(bid0 + r) * 128 + tstep) * 1024
                                   + 16 * wv + 128 * t + n];
        }

        floatx4 acc[8] = {};
        half8 s6[2], s7[2];
        s6[0] = *(const half8*)(wbase6);
        s7[0] = *(const half8*)(wbase7);
#pragma unroll
        for (int kk = 0; kk < 8; ++kk) {
            const int cur = kk & 1, nxt = cur ^ 1;
            if (kk < 7) {
                s6[nxt] = *(const half8*)(wbase6 + (kk + 1) * 32);
                s7[nxt] = *(const half8*)(wbase7 + (kk + 1) * 32);
            }
            half8 a  = *(const half8*)&hbuf[p][kk * 512 + lane * 8];
            half8 b0 = *(const half8*)&ldsB[((wv << 3) | kk) * 512 + lane * 8];
            half8 b1 = *(const half8*)&ldsB[((1 << 6) | (wv << 3) | kk) * 512 + lane * 8];
            acc[0] = __builtin_amdgcn_mfma_f32_16x16x32_f16(a, b0, acc[0], 0, 0, 0);
            acc[1] = __builtin_amdgcn_mfma_f32_16x16x32_f16(a, b1, acc[1], 0, 0, 0);
#pragma unroll
            for (int t = 2; t < 6; ++t)
                acc[t] = __builtin_amdgcn_mfma_f32_16x16x32_f16(a, wreg[t - 2][kk], acc[t], 0, 0, 0);
            acc[6] = __builtin_amdgcn_mfma_f32_16x16x32_f16(a, s6[cur], acc[6], 0, 0, 0);
            acc[7] = __builtin_amdgcn_mfma_f32_16x16x32_f16(a, s7[cur], acc[7], 0, 0, 0);
        }

        // h / c update: valid rows are m = r in {0,1} (lanes kg==0 only)
        if (kg == 0) {
#pragma unroll
            for (int t0 = 0; t0 < 2; ++t0) {
                const int u = 128 * t0 + 16 * wv + n;
                const int kkw = u >> 5;
                const int lgrp = 16 * ((u >> 3) & 3);
                const int e = u & 7;
#pragma unroll
                for (int r = 0; r < 2; ++r) {
                    float gi = acc[t0][r]     + xpv[t0][r];
                    float gf = acc[t0 + 2][r] + xpv[t0 + 2][r];
                    float gg = acc[t0 + 4][r] + xpv[t0 + 4][r];
                    float go = acc[t0 + 6][r] + xpv[t0 + 6][r];
                    float c = cst[t0 * 2 + r];
                    c = sigf(gf) * c + sigf(gi) * tanhf(gg);
                    cst[t0 * 2 + r] = c;
                    float h = sigf(go) * tanhf(c);
                    hbuf[p ^ 1][kkw * 512 + (r + lgrp) * 8 + e] = (f16)h;
                    ov[((long)(bid0 + r) * 128 + tstep) * 512 + dir * 256 + u] = h;
                }
            }
        }
        __syncthreads();
        p ^= 1;
    }
}

// ---------------------------------------------------------------------------
// K3: fw_hidden = bw_hidden = f16(node_repres[nodes]); zero row NN of all
// four hidden buffers (runs AFTER lstm, so the xp-overlay is safe).
// ---------------------------------------------------------------------------
__global__ __launch_bounds__(256) void k_init(const int* __restrict__ nodes,
                                              const float* __restrict__ padding,
                                              const float* __restrict__ out_ro,
                                              f16* __restrict__ h0) {
    long i = (long)blockIdx.x * 256 + threadIdx.x;
    if (i >= (long)NN * 64 + 256) return;
    if (i >= (long)NN * 64) {
        int e = (int)(i - (long)NN * 64);      // 0..255
        int buf = e >> 6, c = (e & 63) * 8;
        half8 z = {};
        *(half8*)(h0 + (long)buf * HBUF_HALVES + (long)NN * HDIM + c) = z;
        return;
    }
    int ni = (int)(i >> 6), c = (int)(i & 63) * 8;
    int r = nodes[ni];
    const float* src = (r < NN) ? (out_ro + OV_OFF + (long)r * HDIM + c)
                                : (padding + c);
    float4 v0 = *(const float4*)src;
    float4 v1 = *(const float4*)(src + 4);
    half8 h;
    h[0] = (f16)v0.x; h[1] = (f16)v0.y; h[2] = (f16)v0.z; h[3] = (f16)v0.w;
    h[4] = (f16)v1.x; h[5] = (f16)v1.y; h[6] = (f16)v1.z; h[7] = (f16)v1.w;
    *(half8*)(h0 + (long)ni * HDIM + c) = h;                      // fw buf 0
    *(half8*)(h0 + 2 * HBUF_HALVES + (long)ni * HDIM + c) = h;    // bw buf 0
}

// ---------------------------------------------------------------------------
// K4a: neighbor mean (+ len at layer 0). One wave per node, 4 nodes/block.
// ---------------------------------------------------------------------------
__global__ __launch_bounds__(256) void k_mean(const int* __restrict__ adj,
                                              const int* __restrict__ nodes,
                                              const f16* __restrict__ src,
                                              const float* __restrict__ ov,
                                              const float* __restrict__ padding,
                                              f16* __restrict__ mean,
                                              float* __restrict__ len,
                                              int layer0) {
    const int w = threadIdx.x >> 6;
    const int lane = threadIdx.x & 63;
    const int i = blockIdx.x * 4 + w;
    const int p0 = lane * 8;
    const int node = nodes[i];
    float acc[8] = {};
    float cnt = 0.0f;
    for (int s = 0; s < SS; ++s) {
        const int r = adj[(long)node * SS + s];
        if (layer0) {
            const float* row = (r < NN) ? (ov + (long)r * HDIM) : padding;
            float4 v0 = *(const float4*)(row + p0);
            float4 v1 = *(const float4*)(row + p0 + 4);
            acc[0] += v0.x; acc[1] += v0.y; acc[2] += v0.z; acc[3] += v0.w;
            acc[4] += v1.x; acc[5] += v1.y; acc[6] += v1.z; acc[7] += v1.w;
            float rs = fmaxf(v0.x, 0.f) + fmaxf(v0.y, 0.f) + fmaxf(v0.z, 0.f) + fmaxf(v0.w, 0.f)
                     + fmaxf(v1.x, 0.f) + fmaxf(v1.y, 0.f) + fmaxf(v1.z, 0.f) + fmaxf(v1.w, 0.f);
#pragma unroll
            for (int off = 32; off; off >>= 1) rs += __shfl_xor(rs, off);
            cnt += (rs > 0.0f) ? 1.0f : 0.0f;
        } else {
            half8 v = *(const half8*)(src + (long)r * HDIM + p0);
#pragma unroll
            for (int j = 0; j < 8; ++j) acc[j] += (float)v[j];
        }
    }
    float ln;
    if (layer0) {
        if (lane == 0) len[i] = cnt;
        ln = cnt;
    } else {
        ln = len[i];
    }
    half8 o;
#pragma unroll
    for (int j = 0; j < 8; ++j) o[j] = (f16)(acc[j] / ln);
    *(half8*)(mean + (long)i * HDIM + p0) = o;
}

// ---------------------------------------------------------------------------
// K4b: out = relu(concat[self, mean] @ W^T + b) via f16 MFMA.
// M=16384, N=512, K=1024. Tile BM=128 x BN=128, BK=64. 4 waves (2x2),
// each wave owns a 64x64 sub-tile (16 MFMAs per 32-K slice).
// ---------------------------------------------------------------------------
__global__ __launch_bounds__(256) void k_sage(const f16* __restrict__ selfH,
                                              const f16* __restrict__ meanH,
                                              const f16* __restrict__ WH,
                                              const float* __restrict__ bl,
                                              f16* __restrict__ outH) {
    const int m0 = blockIdx.x * 128;
    const int q0 = blockIdx.y * 128;
    __shared__ __align__(16) f16 At[128 * 72];
    __shared__ __align__(16) f16 Bt[128 * 72];
    const int tid = threadIdx.x;
    const int wid = tid >> 6;
    const int lane = tid & 63;
    const int wr = wid >> 1, wc = wid & 1;
    const int ln15 = lane & 15, hi = lane >> 4;
    const int ar = tid >> 1, acS = (tid & 1) * 32;

    floatx4 acc[4][4] = {};
    float4 av0, av1, av2, av3, bv0, bv1, bv2, bv3;

    {
        const f16* as = selfH + ((long)(m0 + ar) << 9) + acS;
        av0 = *(const float4*)(const void*)as;
        av1 = *(const float4*)(const void*)(as + 8);
        av2 = *(const float4*)(const void*)(as + 16);
        av3 = *(const float4*)(const void*)(as + 24);
        const f16* bs = WH + ((long)(q0 + ar) << 10) + acS;
        bv0 = *(const float4*)(const void*)bs;
        bv1 = *(const float4*)(const void*)(bs + 8);
        bv2 = *(const float4*)(const void*)(bs + 16);
        bv3 = *(const float4*)(const void*)(bs + 24);
    }

    for (int k0 = 0; k0 < 1024; k0 += 64) {
        __syncthreads();
        *(float4*)(void*)&At[ar * 72 + acS]      = av0;
        *(float4*)(void*)&At[ar * 72 + acS + 8]  = av1;
        *(float4*)(void*)&At[ar * 72 + acS + 16] = av2;
        *(float4*)(void*)&At[ar * 72 + acS + 24] = av3;
        *(float4*)(void*)&Bt[ar * 72 + acS]      = bv0;
        *(float4*)(void*)&Bt[ar * 72 + acS + 8]  = bv1;
        *(float4*)(void*)&Bt[ar * 72 + acS + 16] = bv2;
        *(float4*)(void*)&Bt[ar * 72 + acS + 24] = bv3;
        __syncthreads();

        if (k0 + 64 < 1024) {
            const int kn = k0 + 64;
            const f16* as = (kn < 512)
                ? selfH + ((long)(m0 + ar) << 9) + kn + acS
                : meanH + ((long)(m0 + ar) << 9) + (kn - 512) + acS;
            av0 = *(const float4*)(const void*)as;
            av1 = *(const float4*)(const void*)(as + 8);
            av2 = *(const float4*)(const void*)(as + 16);
            av3 = *(const float4*)(const void*)(as + 24);
            const f16* bs = WH + ((long)(q0 + ar) << 10) + kn + acS;
            bv0 = *(const float4*)(const void*)bs;
            bv1 = *(const float4*)(const void*)(bs + 8);
            bv2 = *(const float4*)(const void*)(bs + 16);
            bv3 = *(const float4*)(const void*)(bs + 24);
        }

#pragma unroll
        for (int ks = 0; ks < 2; ++ks) {
            half8 a[4], b[4];
#pragma unroll
            for (int mi = 0; mi < 4; ++mi)
                a[mi] = *(const half8*)(const void*)&At[(wr * 64 + mi * 16 + ln15) * 72 + ks * 32 + hi * 8];
#pragma unroll
            for (int ni = 0; ni < 4; ++ni)
                b[ni] = *(const half8*)(const void*)&Bt[(wc * 64 + ni * 16 + ln15) * 72 + ks * 32 + hi * 8];
#pragma unroll
            for (int mi = 0; mi < 4; ++mi)
#pragma unroll
                for (int ni = 0; ni < 4; ++ni)
                    acc[mi][ni] = __builtin_amdgcn_mfma_f32_16x16x32_f16(a[mi], b[ni], acc[mi][ni], 0, 0, 0);
        }
    }

#pragma unroll
    for (int ni = 0; ni < 4; ++ni) {
        const int gc = q0 + wc * 64 + ni * 16 + ln15;
        const float bv = bl[gc];
#pragma unroll
        for (int mi = 0; mi < 4; ++mi) {
            const int gr = m0 + wr * 64 + mi * 16 + hi * 4;
#pragma unroll
            for (int r = 0; r < 4; ++r) {
                float v = acc[mi][ni][r] + bv;
                v = fmaxf(v, 0.0f);
                outH[(long)(gr + r) * HDIM + gc] = (f16)v;
            }
        }
    }
}

// ---------------------------------------------------------------------------
// K5: hidden = concat[fw, bw] (B,L,1024) fp32; graph_embedding = max over L.
// ---------------------------------------------------------------------------
__global__ __launch_bounds__(256) void k_final(const f16* __restrict__ fwF,
                                               const f16* __restrict__ bwF,
                                               float* __restrict__ out) {
    const int b = blockIdx.x >> 2;
    const int j = (blockIdx.x & 3) * 256 + threadIdx.x;   // 0..1023
    const f16* __restrict__ src = (j < HDIM) ? fwF : bwF;
    const int jj = (j < HDIM) ? j : j - HDIM;
    float mx = -INFINITY;
    float* __restrict__ hid = out + HID_OFF;
#pragma unroll 4
    for (int l = 0; l < LL; ++l) {
        float v = (float)src[(long)(b * LL + l) * HDIM + jj];
        hid[(long)b * LL * 1024 + (long)l * 1024 + j] = v;
        mx = fmaxf(mx, v);
    }
    out[GE_OFF + (long)b * 1024 + j] = mx;
}

// ---------------------------------------------------------------------------
extern "C" void kernel_launch(void* const* d_in, const int* in_sizes, int n_in,
                              void* d_out, int out_size, void* d_ws, size_t ws_size,
                              hipStream_t stream) {
    const int*   feature_info = (const int*)d_in[0];
    const int*   batch_nodes  = (const int*)d_in[1];
    const int*   fw_adj       = (const int*)d_in[2];
    const int*   bw_adj       = (const int*)d_in[3];
    const float* W_emb        = (const float*)d_in[4];
    const float* Wih_f        = (const float*)d_in[5];
    const float* Whh_f        = (const float*)d_in[6];
    const float* bih_f        = (const float*)d_in[7];
    const float* bhh_f        = (const float*)d_in[8];
    const float* Wih_b        = (const float*)d_in[9];
    const float* Whh_b        = (const float*)d_in[10];
    const float* bih_b        = (const float*)d_in[11];
    const float* bhh_b        = (const float*)d_in[12];
    const float* padding      = (const float*)d_in[13];
    const float* fw_W         = (const float*)d_in[14];
    const float* fw_bias      = (const float*)d_in[15];
    const float* bw_W         = (const float*)d_in[16];
    const float* bw_bias      = (const float*)d_in[17];
    float* out = (float*)d_out;
    float* ws  = (float*)d_ws;
    char*  wsb = (char*)d_ws;

    f16* h0    = (f16*)(wsb + WSB_H0);
    f16* wf16  = (f16*)(wsb + WSB_WF16);
    f16* meanH = (f16*)(wsb + WSB_MEAN);
    f16* whh16 = (f16*)(wsb + WSB_WHH16);
    f16* fwH[2] = { h0,                    h0 + HBUF_HALVES };
    f16* bwH[2] = { h0 + 2 * HBUF_HALVES,  h0 + 3 * HBUF_HALVES };

    k_prep<<<2056, 256, 0, stream>>>(Whh_f, Whh_b, bih_f, bhh_f, bih_b, bhh_b, ws, whh16);
    k_wconv<<<7168, 256, 0, stream>>>(fw_W, bw_W, wf16);
    k_xp<<<dim3(256, 32), 256, 0, stream>>>(feature_info, W_emb, Wih_f, Wih_b, ws);
    k_lstm<<<128, 512, 0, stream>>>(ws, whh16, out);
    k_init<<<4097, 256, 0, stream>>>(batch_nodes, padding, out, h0);

    int fc = 0, bc = 0;
    for (int l = 0; l < NLAYERS; ++l) {
        k_mean<<<4096, 256, 0, stream>>>(fw_adj, batch_nodes, fwH[fc], out + OV_OFF,
                                         padding, meanH, ws + OFF_LENF, l == 0);
        k_sage<<<dim3(128, 4), 256, 0, stream>>>(fwH[fc], meanH,
                                                 wf16 + (long)l * HDIM * G4,
                                                 fw_bias + (long)l * HDIM, fwH[fc ^ 1]);
        fc ^= 1;
        k_mean<<<4096, 256, 0, stream>>>(bw_adj, batch_nodes, bwH[bc], out + OV_OFF,
                                         padding, meanH, ws + OFF_LENB, l == 0);
        k_sage<<<dim3(128, 4), 256, 0, stream>>>(bwH[bc], meanH,
                                                 wf16 + WF16_PER_DIR + (long)l * HDIM * G4,
                                                 bw_bias + (long)l * HDIM, bwH[bc ^ 1]);
        bc ^= 1;
    }
    k_final<<<512, 256, 0, stream>>>(fwH[fc], bwH[bc], out);
}